// Round 8
// baseline (747.298 us; speedup 1.0000x reference)
//
#include <hip/hip_runtime.h>

#define EMB   1024
#define SEQ   2048
#define BATCH 4
#define HEADS 16
#define HDIM  64
#define MTOT  8192

typedef __bf16 bf16x8 __attribute__((ext_vector_type(8)));
typedef float  fx4    __attribute__((ext_vector_type(4)));

#if __has_builtin(__builtin_amdgcn_exp2f)
#define EXP2(x) __builtin_amdgcn_exp2f(x)
#else
#define EXP2(x) exp2f(x)
#endif

__device__ __forceinline__ unsigned short f2bf(float f) {
    unsigned u = __builtin_bit_cast(unsigned, f);
    u += 0x7fffu + ((u >> 16) & 1u);   // RNE
    return (unsigned short)(u >> 16);
}
__device__ __forceinline__ unsigned short bfbits(float f) {
    __bf16 h = (__bf16)f;
    return __builtin_bit_cast(unsigned short, h);
}

#define AS1 __attribute__((address_space(1)))
#define AS3 __attribute__((address_space(3)))
__device__ __forceinline__ void glds16(const void* g, void* l) {
    __builtin_amdgcn_global_load_lds((AS1 void*)g, (AS3 void*)l, 16, 0, 0);
}
// vmcnt(0), expcnt/lgkmcnt unconstrained (gfx9 encoding).
#define DRAIN_GLDS() __builtin_amdgcn_s_waitcnt(0x0f70)

// Raw barrier + compiler memory fence; counted vmcnt waits for the pipeline.
#define BAR()     asm volatile("s_barrier" ::: "memory")
#define WAITV4()  asm volatile("s_waitcnt vmcnt(4)" ::: "memory")
#define WAITV0()  asm volatile("s_waitcnt vmcnt(0)" ::: "memory")
#define WAITLG0() asm volatile("s_waitcnt lgkmcnt(0)" ::: "memory")

// log2(e)/32 — folded into Q so softmax is exp2(s) with no further scaling.
#define QSCALE 0.0450842137604569f

// ---------------------------------------------------------------------------
// x [8192x1024] fp32 -> bf16
// ---------------------------------------------------------------------------
__global__ __launch_bounds__(256) void cvt_x_kernel(const float* __restrict__ x,
                                                    unsigned short* __restrict__ xb)
{
    const int idx = (blockIdx.x * 256 + threadIdx.x) * 4;
    const float4 v = *(const float4*)(x + idx);
    ushort4 o;
    o.x = f2bf(v.x); o.y = f2bf(v.y); o.z = f2bf(v.z); o.w = f2bf(v.w);
    *(ushort4*)(xb + idx) = o;
}

// ---------------------------------------------------------------------------
// W [K][N] fp32 -> Wt [N][K] bf16 (transpose), 4 matrices via grid.z
// ---------------------------------------------------------------------------
__global__ __launch_bounds__(256) void cvt_w_kernel(
    const float* __restrict__ w0, const float* __restrict__ w1,
    const float* __restrict__ w2, const float* __restrict__ w3,
    unsigned short* __restrict__ o0, unsigned short* __restrict__ o1,
    unsigned short* __restrict__ o2, unsigned short* __restrict__ o3)
{
    const int z = blockIdx.z;
    const float* W = z == 0 ? w0 : (z == 1 ? w1 : (z == 2 ? w2 : w3));
    unsigned short* O = z == 0 ? o0 : (z == 1 ? o1 : (z == 2 ? o2 : o3));

    __shared__ float Ws[64][65];
    const int t  = threadIdx.x;
    const int k0 = blockIdx.x * 64, n0 = blockIdx.y * 64;
#pragma unroll
    for (int p = 0; p < 4; ++p) {
        const int row = p * 16 + (t >> 4);
        const int col = (t & 15) * 4;
        const float4 v = *(const float4*)(W + (size_t)(k0 + row) * EMB + n0 + col);
        Ws[row][col]     = v.x; Ws[row][col + 1] = v.y;
        Ws[row][col + 2] = v.z; Ws[row][col + 3] = v.w;
    }
    __syncthreads();
    const int nn = t >> 2;
    const int kb = (t & 3) * 16;
#pragma unroll
    for (int q = 0; q < 2; ++q) {
        const int kk = kb + q * 8;
        ushort4 u0, u1;
        u0.x = f2bf(Ws[kk + 0][nn]); u0.y = f2bf(Ws[kk + 1][nn]);
        u0.z = f2bf(Ws[kk + 2][nn]); u0.w = f2bf(Ws[kk + 3][nn]);
        u1.x = f2bf(Ws[kk + 4][nn]); u1.y = f2bf(Ws[kk + 5][nn]);
        u1.z = f2bf(Ws[kk + 6][nn]); u1.w = f2bf(Ws[kk + 7][nn]);
        *(ushort4*)(O + (size_t)(n0 + nn) * EMB + k0 + kk)     = u0;
        *(ushort4*)(O + (size_t)(n0 + nn) * EMB + k0 + kk + 4) = u1;
    }
}

// ---------------------------------------------------------------------------
// QKV GEMM, 256x256 tile, 512 thr (8 waves = 2M x 4N), 2-SLOT ring (round 8).
// Round 7 (4 slots, 128 KB) ran 1 block/CU: chip-wide barrier lockstep made
// the 96 KB/step of ds_read traffic serialize with MFMA -> 33% eff + 1.5-round
// dispatch tail. This version: 64 KB LDS -> 2 blocks/CU -> ALL 384 blocks
// co-resident (no tail) + cross-block overlap covers the read phases.
//
// Step s (slot = s&1):
//   12 ds_read frags from slot  |  lgkmcnt(0) + BAR   (all waves' reads done)
//   stage subtile s+2 -> SAME slot (4 glds; WAR-free: reads just drained)
//   prio1 32 MFMA prio0          (DMA flight hides under compute)
//   vmcnt(4) = wait the OLDEST 4 loads (= subtile s+1, in-order semantics)
//   BAR                          (publish s+1; never drains the new stage)
// Tail: s==30 -> vmcnt(0); s==31 -> no stage, no wait. 2 barriers/step.
//
// LDS: Ls[2 slots][x,W][128 rows][64 shorts] = 64 KB. Each 128B LDS row packs
// TWO m-rows of one 32-K subtile, 8 chunks of 16B; chunk c stores original
// chunk (c ^ (lr&7)). Frag read: lr = base + (low4>>1), chunk =
// (((low4&1)<<2)|quad) ^ (low4>>1) -> 64 lanes hit 64 DISTINCT 16B slots =>
// conflict-free (round 7: SQ_LDS_BANK_CONFLICT = 0, refcheck PASS).
// glds dest linear; swizzle applied on the per-lane GLOBAL source (lrl=lane>>3,
// cch=lane&7, org=cch^lrl -> global row 2*lrl+(org>>2), kchunk org&3).
//
// B = concat [3072][1024] Wt (wqt|wkt|wvt contiguous). Grid 384, XCD-swizzled.
// Epilogue = round-2/7 proven mapping: z = by>>2.
// ---------------------------------------------------------------------------
__global__ __launch_bounds__(512, 4) void gemm_qkv2s_kernel(
    const unsigned short* __restrict__ Xg, const unsigned short* __restrict__ Wg,
    const float* __restrict__ bq, const float* __restrict__ bk,
    const float* __restrict__ bv,
    unsigned short* __restrict__ qb, unsigned short* __restrict__ kb,
    unsigned short* __restrict__ vtb)
{
    __shared__ unsigned short Ls[2][2][128][64];   // [slot][x/W][ldsrow][64]

    // XCD swizzle (384 % 8 == 0 -> bijective)
    int lin = blockIdx.x;
    lin = (lin & 7) * 48 + (lin >> 3);
    const int bx  = lin & 31;           // m-tile (32)
    const int by  = lin >> 5;           // e-tile (12)
    const int m0  = bx * 256;
    const int e0g = by * 256;           // row into [3072][1024] Wt concat

    const int t    = threadIdx.x;
    const int w    = t >> 6;
    const int lane = t & 63;
    const int low4 = lane & 15;
    const int quad = lane >> 4;
    const int wm   = w >> 2;            // 0..1  m half (128 rows)
    const int wn   = w & 3;             // 0..3  e quarter (64 cols)

    // ---- staging geometry: waves 0-3 stage x (mat=0), 4-7 stage W (mat=1) ----
    const int mat = w >> 2;             // 0 = x, 1 = W
    const int wr  = w & 3;              // lds-row block (32 rows each)
    const int lrl = lane >> 3;          // 0..7 lds-row within 8-row call
    const int cch = lane & 7;           // stored chunk
    const int org = cch ^ lrl;          // original chunk (swizzle on source)
    const int grow0 = (mat ? e0g : m0) + wr * 64 + 2 * lrl + (org >> 2);
    const unsigned short* gsrc =
        (mat ? Wg : Xg) + (size_t)grow0 * EMB + (org & 3) * 8;

    // ---- frag-read geometry (hoisted, row-independent) ----
    const int l2  = low4 >> 1;
    const int cs8 = (((((low4 & 1) << 2) | quad)) ^ l2) * 8;  // shorts

    auto stageS = [&](int slot, int sub) {
        const unsigned short* gp = gsrc + sub * 32;
        glds16(gp,            &Ls[slot][mat][wr * 32 +  0][0]);
        glds16(gp + 16 * EMB, &Ls[slot][mat][wr * 32 +  8][0]);
        glds16(gp + 32 * EMB, &Ls[slot][mat][wr * 32 + 16][0]);
        glds16(gp + 48 * EMB, &Ls[slot][mat][wr * 32 + 24][0]);
    };

    fx4 acc[4][8] = {};   // [ni: e-subtile][mi: m-subtile]

    // prologue: stage subtiles 0,1 into slots 0,1; wait subtile 0 (oldest 4).
    stageS(0, 0);
    stageS(1, 1);
    WAITV4();
    BAR();

#pragma unroll 2
    for (int s = 0; s < 32; ++s) {
        const int slot = s & 1;
        unsigned short (*LX)[64] = Ls[slot][0];   // x rows (m-indexed)
        unsigned short (*LW)[64] = Ls[slot][1];   // W rows (e-indexed)

        bf16x8 af[4], xf[8];
#pragma unroll
        for (int ni = 0; ni < 4; ++ni)
            af[ni] = *(const bf16x8*)&LW[wn * 32 + ni * 8 + l2][cs8];   // A = W
#pragma unroll
        for (int j = 0; j < 8; ++j)
            xf[j] = *(const bf16x8*)&LX[wm * 64 + j * 8 + l2][cs8];     // B = x

        WAITLG0();            // own reads drained (data in regs)
        BAR();                // ALL waves' reads of this slot drained

        if (s <= 29) stageS(slot, s + 2);   // WAR-free: slot just drained

        __builtin_amdgcn_s_setprio(1);
#pragma unroll
        for (int ni = 0; ni < 4; ++ni)
#pragma unroll
            for (int j = 0; j < 8; ++j)
                acc[ni][j] = __builtin_amdgcn_mfma_f32_16x16x32_bf16(
                    af[ni], xf[j], acc[ni][j], 0, 0, 0);
        __builtin_amdgcn_s_setprio(0);

        if (s <= 29)       WAITV4();   // oldest 4 (= subtile s+1) landed
        else if (s == 30)  WAITV0();   // last tile resident
        BAR();                         // publish subtile s+1
    }

    // ---------------- epilogue (round-2/7 proven mapping) ----------------
    const int z   = by >> 2;
    const int eLb = (by & 3) * 256 + wn * 64;      // e_local base of wave
    const float* bias = z == 0 ? bq : (z == 1 ? bk : bv);
    fx4 bvv[4];
#pragma unroll
    for (int ni = 0; ni < 4; ++ni)
        bvv[ni] = *(const fx4*)(bias + eLb + ni * 16 + quad * 4);

    if (z <= 1) {
        const float scl = (z == 0) ? QSCALE : 1.0f;
        unsigned short* o = (z == 0) ? qb : kb;
#pragma unroll
        for (int ni = 0; ni < 4; ++ni)
#pragma unroll
            for (int mi = 0; mi < 8; ++mi) {
                const int m  = m0 + wm * 128 + mi * 16 + low4;
                const int eL = eLb + ni * 16 + quad * 4;
                const int bb = m >> 11, n = m & (SEQ - 1);
                const int hh = eL >> 6, db = eL & 63;
                ushort4 o4;
                o4.x = f2bf((acc[ni][mi][0] + bvv[ni][0]) * scl);
                o4.y = f2bf((acc[ni][mi][1] + bvv[ni][1]) * scl);
                o4.z = f2bf((acc[ni][mi][2] + bvv[ni][2]) * scl);
                o4.w = f2bf((acc[ni][mi][3] + bvv[ni][3]) * scl);
                *(ushort4*)(o + (((size_t)(bb * HEADS + hh)) * SEQ + n) * HDIM + db) = o4;
            }
    } else {
        // V: per 64-row g-block, the 4 mi-frags give the 4 consecutive
        // permuted columns np = low4*4 + j  ->  one ushort4 per (ni, g, rr).
        unsigned short* o = vtb;
#pragma unroll
        for (int ni = 0; ni < 4; ++ni) {
            const int eL = eLb + ni * 16 + quad * 4;
            const int hh = eL >> 6, db = eL & 63;
#pragma unroll
            for (int g = 0; g < 2; ++g) {
                const int mb = m0 + wm * 128 + g * 64;   // 64-aligned block base
                const int bb = mb >> 11;
                const int nb = mb & (SEQ - 1);
#pragma unroll
                for (int rr = 0; rr < 4; ++rr) {
                    ushort4 o4;
                    o4.x = f2bf(acc[ni][g * 4 + 0][rr] + bvv[ni][rr]);
                    o4.y = f2bf(acc[ni][g * 4 + 1][rr] + bvv[ni][rr]);
                    o4.z = f2bf(acc[ni][g * 4 + 2][rr] + bvv[ni][rr]);
                    o4.w = f2bf(acc[ni][g * 4 + 3][rr] + bvv[ni][rr]);
                    *(ushort4*)(o + (((size_t)(bb * HEADS + hh)) * HDIM + db + rr) * SEQ
                                  + nb + low4 * 4) = o4;
                }
            }
        }
    }
}

// ---------------------------------------------------------------------------
// bf16 MFMA GEMM, 128x128 tile, BK=64, serialized (round-3 proven) — retained
// for the output projection (mode 1, fp32 out [M][E]).
// ---------------------------------------------------------------------------
__global__ __launch_bounds__(256) void gemm_bf16_kernel(
    const unsigned short* __restrict__ Ag,
    const unsigned short* __restrict__ B0, const unsigned short* __restrict__ B1,
    const unsigned short* __restrict__ B2,
    const float* __restrict__ bias0, const float* __restrict__ bias1,
    const float* __restrict__ bias2,
    void* out0, void* out1, void* out2, int mode)
{
    const int z = blockIdx.z;
    const unsigned short* __restrict__ Bg = z == 0 ? B0 : (z == 1 ? B1 : B2);
    const float* __restrict__ bias = z == 0 ? bias0 : (z == 1 ? bias1 : bias2);
    void* outp = z == 0 ? out0 : (z == 1 ? out1 : out2);

    __shared__ unsigned short As[128][64];   // x rows   (chunk-swizzled)
    __shared__ unsigned short Bs[128][64];   // W rows   (chunk-swizzled)

    const int t    = threadIdx.x;
    const int w    = t >> 6;
    const int lane = t & 63;
    const int low4 = lane & 15;
    const int quad = lane >> 4;
    const int m0 = blockIdx.x * 128;
    const int e0 = blockIdx.y * 128;
    const int we = (w & 1) * 64;     // e-offset of this wave
    const int wm = (w >> 1) * 64;    // m-offset of this wave

    const int srow8  = lane >> 3;                 // 0..7 within 8-row group
    const int schunk = (lane & 7) ^ srow8;        // swizzled 16B chunk

    fx4 acc[4][4] = {};   // [i: e-subtile][j: m-subtile]

    for (int k0 = 0; k0 < EMB; k0 += 64) {
        __syncthreads();
        const unsigned short* ap = Ag + (size_t)(m0 + w * 32 + srow8) * EMB + k0 + schunk * 8;
        const unsigned short* bp = Bg + (size_t)(e0 + w * 32 + srow8) * EMB + k0 + schunk * 8;
        glds16(ap,            &As[w * 32 +  0][0]);
        glds16(ap +  8 * EMB, &As[w * 32 +  8][0]);
        glds16(ap + 16 * EMB, &As[w * 32 + 16][0]);
        glds16(ap + 24 * EMB, &As[w * 32 + 24][0]);
        glds16(bp,            &Bs[w * 32 +  0][0]);
        glds16(bp +  8 * EMB, &Bs[w * 32 +  8][0]);
        glds16(bp + 16 * EMB, &Bs[w * 32 + 16][0]);
        glds16(bp + 24 * EMB, &Bs[w * 32 + 24][0]);
        DRAIN_GLDS();
        __syncthreads();

#pragma unroll
        for (int ks = 0; ks < 2; ++ks) {
            const int fch = ((ks * 4 + quad) ^ (low4 & 7)) * 8;  // row-indep.
            bf16x8 af[4], bfr[4];
#pragma unroll
            for (int i = 0; i < 4; ++i)
                af[i] = *(const bf16x8*)&Bs[we + i * 16 + low4][fch];   // A = W
#pragma unroll
            for (int j = 0; j < 4; ++j)
                bfr[j] = *(const bf16x8*)&As[wm + j * 16 + low4][fch];  // B = x
#pragma unroll
            for (int i = 0; i < 4; ++i)
#pragma unroll
                for (int j = 0; j < 4; ++j)
                    acc[i][j] = __builtin_amdgcn_mfma_f32_16x16x32_bf16(af[i], bfr[j], acc[i][j], 0, 0, 0);
        }
    }

    fx4 bv[4];
#pragma unroll
    for (int i = 0; i < 4; ++i)
        bv[i] = *(const fx4*)(bias + e0 + we + i * 16 + quad * 4);

    if (mode == 1) {
#pragma unroll
        for (int i = 0; i < 4; ++i)
#pragma unroll
            for (int j = 0; j < 4; ++j) {
                const int m  = m0 + wm + j * 16 + low4;
                const int eb = e0 + we + i * 16 + quad * 4;
                fx4 o4;
#pragma unroll
                for (int rr = 0; rr < 4; ++rr) o4[rr] = acc[i][j][rr] + bv[i][rr];
                *(fx4*)((float*)outp + (size_t)m * EMB + eb) = o4;
            }
    } else if (z <= 1) {
        const float sc = (z == 0) ? QSCALE : 1.0f;
        unsigned short* o = (unsigned short*)outp;
#pragma unroll
        for (int i = 0; i < 4; ++i)
#pragma unroll
            for (int j = 0; j < 4; ++j) {
                const int m  = m0 + wm + j * 16 + low4;
                const int eb = e0 + we + i * 16 + quad * 4;
                const int bb = m >> 11, n = m & (SEQ - 1);
                const int hh = eb >> 6, db = eb & 63;
                ushort4 o4;
                o4.x = f2bf((acc[i][j][0] + bv[i][0]) * sc);
                o4.y = f2bf((acc[i][j][1] + bv[i][1]) * sc);
                o4.z = f2bf((acc[i][j][2] + bv[i][2]) * sc);
                o4.w = f2bf((acc[i][j][3] + bv[i][3]) * sc);
                *(ushort4*)(o + (((size_t)(bb * HEADS + hh)) * SEQ + n) * HDIM + db) = o4;
            }
    } else {
        unsigned short* o = (unsigned short*)outp;
        const int mbase = m0 + wm;
        const int bb    = mbase >> 11;
        const int nb    = mbase & (SEQ - 1);
#pragma unroll
        for (int i = 0; i < 4; ++i) {
            const int eb = e0 + we + i * 16 + quad * 4;
            const int hh = eb >> 6, db = eb & 63;
#pragma unroll
            for (int rr = 0; rr < 4; ++rr) {
                ushort4 o4;
                o4.x = f2bf(acc[i][0][rr] + bv[i][rr]);
                o4.y = f2bf(acc[i][1][rr] + bv[i][rr]);
                o4.z = f2bf(acc[i][2][rr] + bv[i][rr]);
                o4.w = f2bf(acc[i][3][rr] + bv[i][rr]);
                *(ushort4*)(o + (((size_t)(bb * HEADS + hh)) * HDIM + db + rr) * SEQ
                              + nb + low4 * 4) = o4;
            }
        }
    }
}

// ---------------------------------------------------------------------------
// MFMA flash attention v5: lane-local P (no Ps LDS round-trip at all).
// Swapped QK^T (A=K tau-permuted), V np-permutation is the exact inverse of
// pi(kv') = 16*(kv'&3)+(kv'>>2) -> P packs straight into the PV B-fragment
// in registers. LDS = K/V staging only (32 KB).
// ---------------------------------------------------------------------------
__global__ __launch_bounds__(256, 2) void attn_mfma5_kernel(
    const unsigned short* __restrict__ qg, const unsigned short* __restrict__ kg,
    const unsigned short* __restrict__ vg, unsigned short* __restrict__ attb)
{
    __shared__ unsigned short Ks[2][64][64];      // [buf][kv][d],  chunk-swizzled
    __shared__ unsigned short Vs[2][64][64];      // [buf][d][kv'], chunk-swizzled

    const int t    = threadIdx.x;
    const int w    = t >> 6;
    const int lane = t & 63;
    const int low4 = lane & 15;
    const int quad = lane >> 4;
    const int q0   = blockIdx.x * 256 + w * 64;
    const int bh   = blockIdx.y;
    const size_t base = (size_t)bh * SEQ * HDIM;

    const int srow8  = lane >> 3;                    // 0..7 within 8-row group
    const int schunk = (lane & 7) ^ srow8;           // swizzled 16B chunk

    const int tr  = 2 * (low4 >> 2) + (low4 & 1) + 8 * ((low4 >> 1) & 1);
    const int x7k = tr & 7;
    const int x7v = low4 & 7;

    bf16x8 aq[4][2];
#pragma unroll
    for (int s = 0; s < 4; ++s) {
        const size_t qrow = base + (size_t)(q0 + s * 16 + low4) * HDIM;
        aq[s][0] = *(const bf16x8*)(qg + qrow + quad * 8);
        aq[s][1] = *(const bf16x8*)(qg + qrow + 32 + quad * 8);
    }

    fx4 o_acc[4][4] = {};
    float l_part[4] = {};
    const fx4 fzero = {0.f, 0.f, 0.f, 0.f};

    {
        const unsigned short* kp = kg + base + (size_t)(w * 16 + srow8) * HDIM + schunk * 8;
        glds16(kp,              &Ks[0][w * 16][0]);
        glds16(kp + 8 * HDIM,   &Ks[0][w * 16 + 8][0]);
        const unsigned short* vp = vg + base + (size_t)(w * 16 + srow8) * SEQ + schunk * 8;
        glds16(vp,              &Vs[0][w * 16][0]);
        glds16(vp + 8 * SEQ,    &Vs[0][w * 16 + 8][0]);
    }

    for (int tt0 = 0; tt0 < SEQ / 64; ++tt0) {
        const int buf = tt0 & 1;
        DRAIN_GLDS();
        __syncthreads();

        bf16x8 kf[4][2], vf[4][2];
#pragma unroll
        for (int tk = 0; tk < 4; ++tk) {
#pragma unroll
            for (int c = 0; c < 2; ++c) {
                kf[tk][c] = *(const bf16x8*)&Ks[buf][tk * 16 + tr][(((c * 4 + quad) ^ x7k)) * 8];
                vf[tk][c] = *(const bf16x8*)&Vs[buf][tk * 16 + low4][(((c * 4 + quad) ^ x7v)) * 8];
            }
        }

        if (tt0 + 1 < SEQ / 64) {
            const int kv1 = (tt0 + 1) * 64;
            const unsigned short* kp = kg + base + (size_t)(kv1 + w * 16 + srow8) * HDIM + schunk * 8;
            glds16(kp,            &Ks[buf ^ 1][w * 16][0]);
            glds16(kp + 8 * HDIM, &Ks[buf ^ 1][w * 16 + 8][0]);
            const unsigned short* vp = vg + base + (size_t)(w * 16 + srow8) * SEQ + kv1 + schunk * 8;
            glds16(vp,            &Vs[buf ^ 1][w * 16][0]);
            glds16(vp + 8 * SEQ,  &Vs[buf ^ 1][w * 16 + 8][0]);
        }

#pragma unroll
        for (int s = 0; s < 4; ++s) {
            fx4 sa[4];
#pragma unroll
            for (int tk = 0; tk < 4; ++tk) {
                sa[tk] = __builtin_amdgcn_mfma_f32_16x16x32_bf16(kf[tk][0], aq[s][0], fzero, 0, 0, 0);
                sa[tk] = __builtin_amdgcn_mfma_f32_16x16x32_bf16(kf[tk][1], aq[s][1], sa[tk], 0, 0, 0);
            }
            float p[4][4];
#pragma unroll
            for (int tk = 0; tk < 4; ++tk)
#pragma unroll
                for (int r = 0; r < 4; ++r)
                    p[tk][r] = EXP2(sa[tk][r]);

            l_part[s] += (((p[0][0] + p[0][1]) + (p[0][2] + p[0][3]))
                        + ((p[1][0] + p[1][1]) + (p[1][2] + p[1][3])))
                       + (((p[2][0] + p[2][1]) + (p[2][2] + p[2][3]))
                        + ((p[3][0] + p[3][1]) + (p[3][2] + p[3][3])));

            bf16x8 pf0, pf1;
#pragma unroll
            for (int tk = 0; tk < 4; ++tk) {
                pf0[tk]     = (__bf16)p[tk][0];
                pf0[4 + tk] = (__bf16)p[tk][1];
                pf1[tk]     = (__bf16)p[tk][2];
                pf1[4 + tk] = (__bf16)p[tk][3];
            }
#pragma unroll
            for (int t2 = 0; t2 < 4; ++t2) {
                o_acc[s][t2] = __builtin_amdgcn_mfma_f32_16x16x32_bf16(vf[t2][0], pf0, o_acc[s][t2], 0, 0, 0);
                o_acc[s][t2] = __builtin_amdgcn_mfma_f32_16x16x32_bf16(vf[t2][1], pf1, o_acc[s][t2], 0, 0, 0);
            }
        }
    }

    float linv[4];
#pragma unroll
    for (int s = 0; s < 4; ++s) {
        float v = l_part[s];
        v += __shfl_xor(v, 16);
        v += __shfl_xor(v, 32);
        linv[s] = 1.0f / v;
    }

    const int bb = bh >> 4, hh = bh & 15;
#pragma unroll
    for (int s = 0; s < 4; ++s) {
        const size_t m = (size_t)bb * SEQ + q0 + s * 16 + low4;
#pragma unroll
        for (int t2 = 0; t2 < 4; ++t2) {
            ushort4 o4;
            o4.x = bfbits(o_acc[s][t2][0] * linv[s]);
            o4.y = bfbits(o_acc[s][t2][1] * linv[s]);
            o4.z = bfbits(o_acc[s][t2][2] * linv[s]);
            o4.w = bfbits(o_acc[s][t2][3] * linv[s]);
            *(ushort4*)(attb + m * EMB + hh * HDIM + t2 * 16 + quad * 4) = o4;
        }
    }
}

extern "C" void kernel_launch(void* const* d_in, const int* in_sizes, int n_in,
                              void* d_out, int out_size, void* d_ws, size_t ws_size,
                              hipStream_t stream)
{
    const float* x  = (const float*)d_in[0];
    const float* Wq = (const float*)d_in[1];
    const float* bq = (const float*)d_in[2];
    const float* Wk = (const float*)d_in[3];
    const float* bk = (const float*)d_in[4];
    const float* Wv = (const float*)d_in[5];
    const float* bv = (const float*)d_in[6];
    const float* Wo = (const float*)d_in[7];
    const float* bo = (const float*)d_in[8];

    unsigned short* ws  = (unsigned short*)d_ws;
    unsigned short* xb  = ws;                  // 8388608
    unsigned short* wqt = xb + 8388608;        // 1048576 each (wqt|wkt|wvt contiguous)
    unsigned short* wkt = wqt + 1048576;
    unsigned short* wvt = wkt + 1048576;
    unsigned short* wot = wvt + 1048576;
    unsigned short* qb  = wot + 1048576;       // 8388608 each
    unsigned short* kbuf = qb + 8388608;
    unsigned short* vtb  = kbuf + 8388608;
    unsigned short* attb = vtb + 8388608;

    cvt_x_kernel<<<8192, 256, 0, stream>>>(x, xb);
    cvt_w_kernel<<<dim3(16, 16, 4), 256, 0, stream>>>(Wq, Wk, Wv, Wo, wqt, wkt, wvt, wot);

    gemm_qkv2s_kernel<<<384, 512, 0, stream>>>(xb, wqt, bq, bk, bv, qb, kbuf, vtb);

    attn_mfma5_kernel<<<dim3(8, 64), 256, 0, stream>>>(qb, kbuf, vtb, attb);

    gemm_bf16_kernel<<<dim3(64, 8, 1), 256, 0, stream>>>(
        attb, wot, wot, wot, bo, bo, bo, d_out, d_out, d_out, 1);
}

// Round 9
// 264.188 us; speedup vs baseline: 2.8287x; 2.8287x over previous
//
#include <hip/hip_runtime.h>

#define EMB   1024
#define SEQ   2048
#define BATCH 4
#define HEADS 16
#define HDIM  64
#define MTOT  8192

typedef __bf16 bf16x8 __attribute__((ext_vector_type(8)));
typedef float  fx4    __attribute__((ext_vector_type(4)));

#if __has_builtin(__builtin_amdgcn_exp2f)
#define EXP2(x) __builtin_amdgcn_exp2f(x)
#else
#define EXP2(x) exp2f(x)
#endif

__device__ __forceinline__ unsigned short f2bf(float f) {
    unsigned u = __builtin_bit_cast(unsigned, f);
    u += 0x7fffu + ((u >> 16) & 1u);   // RNE
    return (unsigned short)(u >> 16);
}
__device__ __forceinline__ unsigned short bfbits(float f) {
    __bf16 h = (__bf16)f;
    return __builtin_bit_cast(unsigned short, h);
}

#define AS1 __attribute__((address_space(1)))
#define AS3 __attribute__((address_space(3)))
__device__ __forceinline__ void glds16(const void* g, void* l) {
    __builtin_amdgcn_global_load_lds((AS1 void*)g, (AS3 void*)l, 16, 0, 0);
}
// vmcnt(0), expcnt/lgkmcnt unconstrained (gfx9 encoding). REQUIRED before the
// barrier that publishes global_load_lds data (round-4 race: compiler does not
// reliably drain LDS-DMA vmcnt at s_barrier when glds is issued far upstream).
#define DRAIN_GLDS() __builtin_amdgcn_s_waitcnt(0x0f70)

// log2(e)/32 — folded into Q so softmax is exp2(s) with no further scaling.
#define QSCALE 0.0450842137604569f

// ---------------------------------------------------------------------------
// x [8192x1024] fp32 -> bf16
// ---------------------------------------------------------------------------
__global__ __launch_bounds__(256) void cvt_x_kernel(const float* __restrict__ x,
                                                    unsigned short* __restrict__ xb)
{
    const int idx = (blockIdx.x * 256 + threadIdx.x) * 4;
    const float4 v = *(const float4*)(x + idx);
    ushort4 o;
    o.x = f2bf(v.x); o.y = f2bf(v.y); o.z = f2bf(v.z); o.w = f2bf(v.w);
    *(ushort4*)(xb + idx) = o;
}

// ---------------------------------------------------------------------------
// W [K][N] fp32 -> Wt [N][K] bf16 (transpose), 4 matrices via grid.z
// ---------------------------------------------------------------------------
__global__ __launch_bounds__(256) void cvt_w_kernel(
    const float* __restrict__ w0, const float* __restrict__ w1,
    const float* __restrict__ w2, const float* __restrict__ w3,
    unsigned short* __restrict__ o0, unsigned short* __restrict__ o1,
    unsigned short* __restrict__ o2, unsigned short* __restrict__ o3)
{
    const int z = blockIdx.z;
    const float* W = z == 0 ? w0 : (z == 1 ? w1 : (z == 2 ? w2 : w3));
    unsigned short* O = z == 0 ? o0 : (z == 1 ? o1 : (z == 2 ? o2 : o3));

    __shared__ float Ws[64][65];
    const int t  = threadIdx.x;
    const int k0 = blockIdx.x * 64, n0 = blockIdx.y * 64;
#pragma unroll
    for (int p = 0; p < 4; ++p) {
        const int row = p * 16 + (t >> 4);
        const int col = (t & 15) * 4;
        const float4 v = *(const float4*)(W + (size_t)(k0 + row) * EMB + n0 + col);
        Ws[row][col]     = v.x; Ws[row][col + 1] = v.y;
        Ws[row][col + 2] = v.z; Ws[row][col + 3] = v.w;
    }
    __syncthreads();
    const int nn = t >> 2;
    const int kb = (t & 3) * 16;
#pragma unroll
    for (int q = 0; q < 2; ++q) {
        const int kk = kb + q * 8;
        ushort4 u0, u1;
        u0.x = f2bf(Ws[kk + 0][nn]); u0.y = f2bf(Ws[kk + 1][nn]);
        u0.z = f2bf(Ws[kk + 2][nn]); u0.w = f2bf(Ws[kk + 3][nn]);
        u1.x = f2bf(Ws[kk + 4][nn]); u1.y = f2bf(Ws[kk + 5][nn]);
        u1.z = f2bf(Ws[kk + 6][nn]); u1.w = f2bf(Ws[kk + 7][nn]);
        *(ushort4*)(O + (size_t)(n0 + nn) * EMB + k0 + kk)     = u0;
        *(ushort4*)(O + (size_t)(n0 + nn) * EMB + k0 + kk + 4) = u1;
    }
}

// ---------------------------------------------------------------------------
// bf16 MFMA GEMM, 128x128 tile, BK=64, serialized stage->drain->compute
// (round-3 structure — best measured: 74.9 µs QKV, total 264.8). Single-buffer
// 32 KB LDS keeps 4-5 blocks/CU so the vmcnt(0) drain is hidden by CROSS-BLOCK
// overlap (m114). Rounds 4/7/8 proved every restructure of this loop
// (intra-block dbuf, 256^2 ring, 2-slot counted-vmcnt) regresses: the 4x8-acc
// register budget (~190) forbids 256^2 co-residency, and 1-block/CU lockstep
// exposes the LDS-read phases. DO NOT restructure; occupancy is the engine.
//
// LDS rows = 64 shorts (128 B) in 8 chunks of 16 B, XOR-swizzled on the
// GLOBAL side: staging lane covers row srow8 = lane>>3, global chunk
// (lane&7)^srow8, so LDS[row][c] = global[row][c ^ (row&7)]. Frag reads
// un-swizzle with chunk = (ks*4+quad)^(low4&7) — measured conflict-free.
// mode 0: z= Q/K/V. Q -> [B,H,N,D]*QSCALE; K -> [B,H,N,D];
//         V -> [B,H,D,N], kv permuted per 64-block: np = (n%16)*4 + (n/16)%4.
// mode 1: fp32 out [M][E].
// ---------------------------------------------------------------------------
__global__ __launch_bounds__(256) void gemm_bf16_kernel(
    const unsigned short* __restrict__ Ag,
    const unsigned short* __restrict__ B0, const unsigned short* __restrict__ B1,
    const unsigned short* __restrict__ B2,
    const float* __restrict__ bias0, const float* __restrict__ bias1,
    const float* __restrict__ bias2,
    void* out0, void* out1, void* out2, int mode)
{
    const int z = blockIdx.z;
    const unsigned short* __restrict__ Bg = z == 0 ? B0 : (z == 1 ? B1 : B2);
    const float* __restrict__ bias = z == 0 ? bias0 : (z == 1 ? bias1 : bias2);
    void* outp = z == 0 ? out0 : (z == 1 ? out1 : out2);

    __shared__ unsigned short As[128][64];   // x rows   (chunk-swizzled)
    __shared__ unsigned short Bs[128][64];   // W rows   (chunk-swizzled)

    const int t    = threadIdx.x;
    const int w    = t >> 6;
    const int lane = t & 63;
    const int low4 = lane & 15;
    const int quad = lane >> 4;
    const int m0 = blockIdx.x * 128;
    const int e0 = blockIdx.y * 128;
    const int we = (w & 1) * 64;     // e-offset of this wave
    const int wm = (w >> 1) * 64;    // m-offset of this wave

    // staging: wave w covers rows w*32 .. w*32+31 of each matrix, 4 glds each.
    const int srow8  = lane >> 3;                 // 0..7 within 8-row group
    const int schunk = (lane & 7) ^ srow8;        // swizzled 16B chunk

    fx4 acc[4][4] = {};   // [i: e-subtile][j: m-subtile]

    for (int k0 = 0; k0 < EMB; k0 += 64) {
        __syncthreads();
        const unsigned short* ap = Ag + (size_t)(m0 + w * 32 + srow8) * EMB + k0 + schunk * 8;
        const unsigned short* bp = Bg + (size_t)(e0 + w * 32 + srow8) * EMB + k0 + schunk * 8;
        glds16(ap,            &As[w * 32 +  0][0]);
        glds16(ap +  8 * EMB, &As[w * 32 +  8][0]);
        glds16(ap + 16 * EMB, &As[w * 32 + 16][0]);
        glds16(ap + 24 * EMB, &As[w * 32 + 24][0]);
        glds16(bp,            &Bs[w * 32 +  0][0]);
        glds16(bp +  8 * EMB, &Bs[w * 32 +  8][0]);
        glds16(bp + 16 * EMB, &Bs[w * 32 + 16][0]);
        glds16(bp + 24 * EMB, &Bs[w * 32 + 24][0]);
        DRAIN_GLDS();
        __syncthreads();

#pragma unroll
        for (int ks = 0; ks < 2; ++ks) {
            const int fch = ((ks * 4 + quad) ^ (low4 & 7)) * 8;  // row-indep.
            bf16x8 af[4], bfr[4];
#pragma unroll
            for (int i = 0; i < 4; ++i)
                af[i] = *(const bf16x8*)&Bs[we + i * 16 + low4][fch];   // A = W
#pragma unroll
            for (int j = 0; j < 4; ++j)
                bfr[j] = *(const bf16x8*)&As[wm + j * 16 + low4][fch];  // B = x
#pragma unroll
            for (int i = 0; i < 4; ++i)
#pragma unroll
                for (int j = 0; j < 4; ++j)
                    acc[i][j] = __builtin_amdgcn_mfma_f32_16x16x32_bf16(af[i], bfr[j], acc[i][j], 0, 0, 0);
        }
    }

    // bias: e = e0 + we + i*16 + quad*4 + rr  (4 consecutive)
    fx4 bv[4];
#pragma unroll
    for (int i = 0; i < 4; ++i)
        bv[i] = *(const fx4*)(bias + e0 + we + i * 16 + quad * 4);

    if (mode == 1) {
#pragma unroll
        for (int i = 0; i < 4; ++i)
#pragma unroll
            for (int j = 0; j < 4; ++j) {
                const int m  = m0 + wm + j * 16 + low4;
                const int eb = e0 + we + i * 16 + quad * 4;
                fx4 o4;
#pragma unroll
                for (int rr = 0; rr < 4; ++rr) o4[rr] = acc[i][j][rr] + bv[i][rr];
                *(fx4*)((float*)outp + (size_t)m * EMB + eb) = o4;
            }
    } else if (z <= 1) {
        const float sc = (z == 0) ? QSCALE : 1.0f;
        unsigned short* o = (unsigned short*)outp;
#pragma unroll
        for (int i = 0; i < 4; ++i)
#pragma unroll
            for (int j = 0; j < 4; ++j) {
                const int m  = m0 + wm + j * 16 + low4;
                const int eb = e0 + we + i * 16 + quad * 4;
                const int bb = m >> 11, n = m & (SEQ - 1);
                const int hh = eb >> 6, db = eb & 63;
                ushort4 o4;
                o4.x = f2bf((acc[i][j][0] + bv[i][0]) * sc);
                o4.y = f2bf((acc[i][j][1] + bv[i][1]) * sc);
                o4.z = f2bf((acc[i][j][2] + bv[i][2]) * sc);
                o4.w = f2bf((acc[i][j][3] + bv[i][3]) * sc);
                *(ushort4*)(o + (((size_t)(bb * HEADS + hh)) * SEQ + n) * HDIM + db) = o4;
            }
    } else {
        // V: for fixed (lane, rr) the four j-subtiles give the 4 consecutive
        // permuted columns np = low4*4 + j  ->  one ushort4 per (i, rr).
        unsigned short* o = (unsigned short*)outp;
        const int mbase = m0 + wm;                  // multiple of 64
        const int bb    = mbase >> 11;
        const int nb    = mbase & (SEQ - 1);        // 64-aligned block base
#pragma unroll
        for (int i = 0; i < 4; ++i) {
            const int eb = e0 + we + i * 16 + quad * 4;
            const int hh = eb >> 6, db = eb & 63;
#pragma unroll
            for (int rr = 0; rr < 4; ++rr) {
                ushort4 o4;
                o4.x = f2bf(acc[i][0][rr] + bv[i][rr]);
                o4.y = f2bf(acc[i][1][rr] + bv[i][rr]);
                o4.z = f2bf(acc[i][2][rr] + bv[i][rr]);
                o4.w = f2bf(acc[i][3][rr] + bv[i][rr]);
                *(ushort4*)(o + (((size_t)(bb * HEADS + hh)) * HDIM + db + rr) * SEQ
                              + nb + low4 * 4) = o4;
            }
        }
    }
}

// ---------------------------------------------------------------------------
// MFMA flash attention v6 = v5 + two catalog levers (round 9):
//  * T1 XCD swizzle: 1-D grid of 512 (512%8==0, bijective wk =
//    (lin&7)*64 + (lin>>3)); each XCD owns 8 whole heads, so the 8 q-tile
//    blocks sharing one head's 512 KB K/V land on ONE XCD's L2 (was: spread
//    round-robin over all 8 -> 8x redundant K/V HBM fetch; round-0 FETCH
//    139 MB vs ~96 ideal).
//  * T5 setprio(1) around the QK^T and PV MFMA clusters (m191: +4-7% on attn
//    — waves between tile barriers are phase-independent, so the CU scheduler
//    has roles to arbitrate).
// Core math unchanged (v5, proven): swapped QK^T (A=K tau-permuted), lane-
// local P, V np-permutation = inverse of pi(kv') -> P packs straight into the
// PV B-fragment in registers. LDS = K/V staging only (32 KB).
// ---------------------------------------------------------------------------
__global__ __launch_bounds__(256, 2) void attn_mfma5_kernel(
    const unsigned short* __restrict__ qg, const unsigned short* __restrict__ kg,
    const unsigned short* __restrict__ vg, unsigned short* __restrict__ attb)
{
    __shared__ unsigned short Ks[2][64][64];      // [buf][kv][d],  chunk-swizzled
    __shared__ unsigned short Vs[2][64][64];      // [buf][d][kv'], chunk-swizzled

    const int t    = threadIdx.x;
    const int w    = t >> 6;
    const int lane = t & 63;
    const int low4 = lane & 15;
    const int quad = lane >> 4;
    // XCD swizzle: work item wk; 8 consecutive wk (one head) per XCD chunk.
    const int wk   = (blockIdx.x & 7) * 64 + (blockIdx.x >> 3);
    const int bh   = wk >> 3;
    const int q0   = (wk & 7) * 256 + w * 64;
    const size_t base = (size_t)bh * SEQ * HDIM;

    const int srow8  = lane >> 3;                    // 0..7 within 8-row group
    const int schunk = (lane & 7) ^ srow8;           // swizzled 16B chunk

    const int tr  = 2 * (low4 >> 2) + (low4 & 1) + 8 * ((low4 >> 1) & 1);
    const int x7k = tr & 7;
    const int x7v = low4 & 7;

    bf16x8 aq[4][2];
#pragma unroll
    for (int s = 0; s < 4; ++s) {
        const size_t qrow = base + (size_t)(q0 + s * 16 + low4) * HDIM;
        aq[s][0] = *(const bf16x8*)(qg + qrow + quad * 8);
        aq[s][1] = *(const bf16x8*)(qg + qrow + 32 + quad * 8);
    }

    fx4 o_acc[4][4] = {};
    float l_part[4] = {};
    const fx4 fzero = {0.f, 0.f, 0.f, 0.f};

    {
        const unsigned short* kp = kg + base + (size_t)(w * 16 + srow8) * HDIM + schunk * 8;
        glds16(kp,              &Ks[0][w * 16][0]);
        glds16(kp + 8 * HDIM,   &Ks[0][w * 16 + 8][0]);
        const unsigned short* vp = vg + base + (size_t)(w * 16 + srow8) * SEQ + schunk * 8;
        glds16(vp,              &Vs[0][w * 16][0]);
        glds16(vp + 8 * SEQ,    &Vs[0][w * 16 + 8][0]);
    }

    for (int tt0 = 0; tt0 < SEQ / 64; ++tt0) {
        const int buf = tt0 & 1;
        DRAIN_GLDS();
        __syncthreads();

        bf16x8 kf[4][2], vf[4][2];
#pragma unroll
        for (int tk = 0; tk < 4; ++tk) {
#pragma unroll
            for (int c = 0; c < 2; ++c) {
                kf[tk][c] = *(const bf16x8*)&Ks[buf][tk * 16 + tr][(((c * 4 + quad) ^ x7k)) * 8];
                vf[tk][c] = *(const bf16x8*)&Vs[buf][tk * 16 + low4][(((c * 4 + quad) ^ x7v)) * 8];
            }
        }

        if (tt0 + 1 < SEQ / 64) {
            const int kv1 = (tt0 + 1) * 64;
            const unsigned short* kp = kg + base + (size_t)(kv1 + w * 16 + srow8) * HDIM + schunk * 8;
            glds16(kp,            &Ks[buf ^ 1][w * 16][0]);
            glds16(kp + 8 * HDIM, &Ks[buf ^ 1][w * 16 + 8][0]);
            const unsigned short* vp = vg + base + (size_t)(w * 16 + srow8) * SEQ + kv1 + schunk * 8;
            glds16(vp,            &Vs[buf ^ 1][w * 16][0]);
            glds16(vp + 8 * SEQ,  &Vs[buf ^ 1][w * 16 + 8][0]);
        }

#pragma unroll
        for (int s = 0; s < 4; ++s) {
            fx4 sa[4];
            __builtin_amdgcn_s_setprio(1);
#pragma unroll
            for (int tk = 0; tk < 4; ++tk) {
                sa[tk] = __builtin_amdgcn_mfma_f32_16x16x32_bf16(kf[tk][0], aq[s][0], fzero, 0, 0, 0);
                sa[tk] = __builtin_amdgcn_mfma_f32_16x16x32_bf16(kf[tk][1], aq[s][1], sa[tk], 0, 0, 0);
            }
            __builtin_amdgcn_s_setprio(0);
            float p[4][4];
#pragma unroll
            for (int tk = 0; tk < 4; ++tk)
#pragma unroll
                for (int r = 0; r < 4; ++r)
                    p[tk][r] = EXP2(sa[tk][r]);

            l_part[s] += (((p[0][0] + p[0][1]) + (p[0][2] + p[0][3]))
                        + ((p[1][0] + p[1][1]) + (p[1][2] + p[1][3])))
                       + (((p[2][0] + p[2][1]) + (p[2][2] + p[2][3]))
                        + ((p[3][0] + p[3][1]) + (p[3][2] + p[3][3])));

            bf16x8 pf0, pf1;
#pragma unroll
            for (int tk = 0; tk < 4; ++tk) {
                pf0[tk]     = (__bf16)p[tk][0];
                pf0[4 + tk] = (__bf16)p[tk][1];
                pf1[tk]     = (__bf16)p[tk][2];
                pf1[4 + tk] = (__bf16)p[tk][3];
            }
            __builtin_amdgcn_s_setprio(1);
#pragma unroll
            for (int t2 = 0; t2 < 4; ++t2) {
                o_acc[s][t2] = __builtin_amdgcn_mfma_f32_16x16x32_bf16(vf[t2][0], pf0, o_acc[s][t2], 0, 0, 0);
                o_acc[s][t2] = __builtin_amdgcn_mfma_f32_16x16x32_bf16(vf[t2][1], pf1, o_acc[s][t2], 0, 0, 0);
            }
            __builtin_amdgcn_s_setprio(0);
        }
    }

    float linv[4];
#pragma unroll
    for (int s = 0; s < 4; ++s) {
        float v = l_part[s];
        v += __shfl_xor(v, 16);
        v += __shfl_xor(v, 32);
        linv[s] = 1.0f / v;
    }

    const int bb = bh >> 4, hh = bh & 15;
#pragma unroll
    for (int s = 0; s < 4; ++s) {
        const size_t m = (size_t)bb * SEQ + q0 + s * 16 + low4;
#pragma unroll
        for (int t2 = 0; t2 < 4; ++t2) {
            ushort4 o4;
            o4.x = bfbits(o_acc[s][t2][0] * linv[s]);
            o4.y = bfbits(o_acc[s][t2][1] * linv[s]);
            o4.z = bfbits(o_acc[s][t2][2] * linv[s]);
            o4.w = bfbits(o_acc[s][t2][3] * linv[s]);
            *(ushort4*)(attb + m * EMB + hh * HDIM + t2 * 16 + quad * 4) = o4;
        }
    }
}

extern "C" void kernel_launch(void* const* d_in, const int* in_sizes, int n_in,
                              void* d_out, int out_size, void* d_ws, size_t ws_size,
                              hipStream_t stream)
{
    const float* x  = (const float*)d_in[0];
    const float* Wq = (const float*)d_in[1];
    const float* bq = (const float*)d_in[2];
    const float* Wk = (const float*)d_in[3];
    const float* bk = (const float*)d_in[4];
    const float* Wv = (const float*)d_in[5];
    const float* bv = (const float*)d_in[6];
    const float* Wo = (const float*)d_in[7];
    const float* bo = (const float*)d_in[8];

    unsigned short* ws  = (unsigned short*)d_ws;
    unsigned short* xb  = ws;                  // 8388608
    unsigned short* wqt = xb + 8388608;        // 1048576 each
    unsigned short* wkt = wqt + 1048576;
    unsigned short* wvt = wkt + 1048576;
    unsigned short* wot = wvt + 1048576;
    unsigned short* qb  = wot + 1048576;       // 8388608 each
    unsigned short* kbuf = qb + 8388608;
    unsigned short* vtb  = kbuf + 8388608;
    unsigned short* attb = vtb + 8388608;

    cvt_x_kernel<<<8192, 256, 0, stream>>>(x, xb);
    cvt_w_kernel<<<dim3(16, 16, 4), 256, 0, stream>>>(Wq, Wk, Wv, Wo, wqt, wkt, wvt, wot);

    gemm_bf16_kernel<<<dim3(64, 8, 3), 256, 0, stream>>>(
        xb, wqt, wkt, wvt, bq, bk, bv, qb, kbuf, vtb, 0);

    attn_mfma5_kernel<<<512, 256, 0, stream>>>(qb, kbuf, vtb, attb);

    gemm_bf16_kernel<<<dim3(64, 8, 1), 256, 0, stream>>>(
        attb, wot, wot, wot, bo, bo, bo, d_out, d_out, d_out, 1);
}